// Round 16
// baseline (91.020 us; speedup 1.0000x reference)
//
#include <hip/hip_runtime.h>

// ---------------------------------------------------------------------------
// MalConvLowMem as GEMM: M=15748 windows (4096 contiguous floats), N=256
// (w1|w2), K=4096; epilogue g=(c1+b1)*sigmoid(c2+b2), max over positions.
// R16 = R12 + SPLIT-K x2 for 2 blocks/CU: each block does BM=64 x 256 over
// 32 K-tiles (kh=0/1), writes partial C (fp32, [kh][bb][mtile][64][256],
// vcol = w*16+cl layout) to d_ws; merge kernel sums halves + gate + max.
// Grid 496 -> 2 blocks/CU, 32 waves/CU (VGPR 48 fits launch_bounds(1024,8),
// LDS 2x64KB=128KB). R12's ring-8 A-LDS + counted lgkmcnt(15) superstep and
// R9/R12 pack_w kept verbatim. ws: Bp 2MB @0, Cpart 33MB @2MB (ws ~1GB).
// ---------------------------------------------------------------------------

#define T_LEN 2000000
#define P_CNT 3937
#define M_TOT 15748
#define KD    4096

typedef __attribute__((ext_vector_type(8))) short short8;
typedef __attribute__((ext_vector_type(4))) float f32x4;

static __device__ __forceinline__ unsigned short f2bf(float f) {
    unsigned u = __builtin_bit_cast(unsigned, f);
    unsigned r = (u + 0x7FFFu + ((u >> 16) & 1u)) >> 16;   // RNE
    return (unsigned short)r;
}

static __device__ __forceinline__ unsigned ordenc(float f) {
    unsigned u = __builtin_bit_cast(unsigned, f);
    return (u & 0x80000000u) ? ~u : (u | 0x80000000u);
}

// (batch bb, position p<=3936) -> flat float offset of window start in x
static __device__ __forceinline__ size_t row_base_bp(int bb, int p) {
    int j, kp;
    if (p < 3875) { j = p / 125; kp = p - j * 125; }
    else          { j = 31;      kp = p - 3875; }
    long pos = (long)j * 63489 + (long)kp * 512;
    return ((size_t)bb * T_LEN + (size_t)pos) * 8u;
}

// 4 fp32 -> 4 bf16 (uint2) via v_cvt_pk_bf16_f32 (RNE)
static __device__ __forceinline__ uint2 cvt4(float4 v) {
    unsigned lo, hi;
    asm("v_cvt_pk_bf16_f32 %0, %1, %2" : "=v"(lo) : "v"(v.x), "v"(v.y));
    asm("v_cvt_pk_bf16_f32 %0, %1, %2" : "=v"(hi) : "v"(v.z), "v"(v.w));
    uint2 u; u.x = lo; u.y = hi;
    return u;
}

// ---------------------------------------------------------------------------
// Kernel 1 (R9/R12, proven): repack weights fragment-major with gate-pair
// col permutation. uint4 chunk c = ((ks*2+kq)*16 + w)*64 + l:
//   cl=l&15; n = cl<8 ? w*8+cl : 128+w*8+(cl-8); k = ks*64+kq*32+(l>>4)*8+0..7
//   W'[n][k] = (n<128?w1:w2)[n&127][e=k&7][t=k>>3] as bf16. Init outu.
// ---------------------------------------------------------------------------
__global__ __launch_bounds__(256) void pack_w(const float* __restrict__ w1,
                                              const float* __restrict__ w2,
                                              uint4* __restrict__ Bpf,
                                              unsigned* __restrict__ outu) {
    int c = blockIdx.x * 256 + threadIdx.x;         // grid 512 -> 131072
    if (c < 512) outu[c] = 0u;
    if (c >= 131072) return;
    int l  = c & 63;
    int w  = (c >> 6) & 15;                          // wave 0..15
    int kq = (c >> 10) & 1;
    int ks = c >> 11;
    int cl = l & 15;
    int n  = (cl < 8) ? (w * 8 + cl) : (128 + w * 8 + (cl - 8));
    int kb = ks * 64 + kq * 32 + ((l >> 4) << 3);
    const float* src = (n < 128) ? w1 : w2;
    int cc = n & 127;
    unsigned short h[8];
#pragma unroll
    for (int j = 0; j < 8; ++j) {
        int k = kb + j;
        h[j] = f2bf(src[cc * 4096 + (k & 7) * 512 + (k >> 3)]);
    }
    uint4 v;
    v.x = (unsigned)h[0] | ((unsigned)h[1] << 16);
    v.y = (unsigned)h[2] | ((unsigned)h[3] << 16);
    v.z = (unsigned)h[4] | ((unsigned)h[5] << 16);
    v.w = (unsigned)h[6] | ((unsigned)h[7] << 16);
    Bpf[c] = v;
}

// ---------------------------------------------------------------------------
// Kernel 2: split-K partial GEMM. 1024 thr / 16 waves, wave tile 64 rows x
// 16 vcols, acc[4] f32x4. A ring-8 in LDS (8 x 8KB). 32 K-tiles per block.
// Superstep = 2 K-tiles, one lgkmcnt(15)+s_barrier (R12 publish proof).
// Epilogue: coalesced fp32 store of partial C to Cpart[kh][bb][mtile][r][vc].
// ---------------------------------------------------------------------------
#define LOAD_B(BB, KT)                                                         \
    do {                                                                       \
        _Pragma("unroll")                                                      \
        for (int kq = 0; kq < 2; ++kq)                                         \
            BB[kq] = Bq[((KT) * 2 + kq) * 1024 + bbase];                       \
    } while (0)

// One K-tile (local idx), NO barrier. Loads A for tile KS+6, writes KS+4 slot.
#define STEP_NB(KS, BCUR, BNXT)                                                \
    do {                                                                       \
        const int ks_ = (KS);                                                  \
        const int ksn = (ks_ + 1 < 32) ? ks_ + 1 : 31;                         \
        LOAD_B(BNXT, kbase + ksn);                                             \
        const int ksl = (ks_ + 6 < 32) ? ks_ + 6 : 31;                         \
        float4 aF = *(const float4*)(x + aoff + (size_t)(ksl * 64));           \
        const char* As = smem + (ks_ & 7) * 8192;                              \
        _Pragma("unroll")                                                      \
        for (int kq = 0; kq < 2; ++kq) {                                       \
            short8 b = __builtin_bit_cast(short8, BCUR[kq]);                   \
            _Pragma("unroll")                                                  \
            for (int mf = 0; mf < 4; ++mf) {                                   \
                short8 af = *(const short8*)(As + aro[kq][mf]);                \
                acc[mf] = __builtin_amdgcn_mfma_f32_16x16x32_bf16(             \
                    af, b, acc[mf], 0, 0, 0);                                  \
            }                                                                  \
        }                                                                      \
        if (ks_ + 4 < 32)                                                      \
            *(uint2*)(smem + ((ks_ + 4) & 7) * 8192 + awb) = cvt4(aA);         \
        aA = aB; aB = aF;                                                      \
    } while (0)

__global__ __launch_bounds__(1024, 8) void gemm_part(const float* __restrict__ x,
                                                     const uint4* __restrict__ Bq,
                                                     float* __restrict__ Cpart) {
    __shared__ __align__(16) char smem[65536];      // ring-8 of 8KB

    const int t    = threadIdx.x;
    const int lane = t & 63;
    const int w    = t >> 6;                        // wave 0..15
    const int bid  = blockIdx.x;
    const int kh   = bid & 1;                       // K-half
    const int rest = bid >> 1;                      // 0..247
    const int bb   = rest / 62;                     // batch
    const int mt   = rest % 62;                     // m-tile
    const int p0   = mt * 64;
    const int kbase = kh * 32;                      // first K-tile

    // ---- A staging: thread t handles row=t>>4 (0..63), k-chunk t&15 ----
    const int rowS = t >> 4;
    const int kcS  = t & 15;
    int pS = p0 + rowS; if (pS > P_CNT - 1) pS = P_CNT - 1;
    const size_t aoff = row_base_bp(bb, pS) + (size_t)(kcS * 4)
                      + (size_t)kbase * 64;
    const int    awb  = (rowS * 128 + kcS * 8) ^ ((rowS & 7) << 4);

    // ---- A fragment read offsets [kq][mf] (XOR-swizzled, 2-way-free) ----
    int aro[2][4];
#pragma unroll
    for (int kq = 0; kq < 2; ++kq)
#pragma unroll
        for (int mf = 0; mf < 4; ++mf) {
            int row = mf * 16 + (lane & 15);
            aro[kq][mf] = (row * 128 + kq * 64 + (lane >> 4) * 16)
                          ^ ((row & 7) << 4);
        }

    const int bbase = w * 64 + lane;                // uint4 units

    // ---- prologue: stage local tiles 0..3 into slots 0..3 ----
#pragma unroll
    for (int pt = 0; pt < 4; ++pt) {
        float4 v = *(const float4*)(x + aoff + pt * 64);
        *(uint2*)(smem + pt * 8192 + awb) = cvt4(v);
    }
    __syncthreads();

    float4 aA = *(const float4*)(x + aoff + 256);   // local tile 4
    float4 aB = *(const float4*)(x + aoff + 320);   // local tile 5
    uint4 BX[2], BY[2];
    LOAD_B(BX, kbase);

    f32x4 acc[4];
#pragma unroll
    for (int mf = 0; mf < 4; ++mf) acc[mf] = (f32x4){0.f, 0.f, 0.f, 0.f};

    // ---- main loop: 16 supersteps of 2 K-tiles, one counted barrier each.
    // Publish proof (R12): write(slot s+4) at step s has >=18 newer DS ops
    // by its 2nd barrier; lgkmcnt(15) + in-order DS retires it first.
    for (int ks = 0; ks < 32; ks += 2) {
        STEP_NB(ks, BX, BY);
        STEP_NB(ks + 1, BY, BX);
        asm volatile("s_waitcnt lgkmcnt(15)" ::: "memory");
        __builtin_amdgcn_s_barrier();
        asm volatile("" ::: "memory");
    }

    // ---- epilogue: coalesced partial-C store (row-major, vcol contig) ----
    float* Cp = Cpart + (((size_t)(kh * 4 + bb) * 62 + mt) << 14);  // *16384
#pragma unroll
    for (int mf = 0; mf < 4; ++mf)
#pragma unroll
        for (int q = 0; q < 4; ++q) {
            int row = mf * 16 + (lane >> 4) * 4 + q;
            Cp[row * 256 + w * 16 + (lane & 15)] = acc[mf][q];
        }
}

// ---------------------------------------------------------------------------
// Kernel 3: merge halves + gate + per-(b,c) max. Block = (bb, mtile),
// 256 thr: c = t&127, row-half = t>>7. 128 atomicMax per block.
// vcol(c1) = (c>>3)*16 + (c&7); vcol(c2) = +8 (R12 pack permutation).
// ---------------------------------------------------------------------------
__global__ __launch_bounds__(256) void merge_max(const float* __restrict__ Cpart,
                                                 const float* __restrict__ b1,
                                                 const float* __restrict__ b2,
                                                 unsigned* __restrict__ outu) {
    __shared__ float red[256];
    const int bid = blockIdx.x;                     // 0..247
    const int bb  = bid / 62;
    const int mt  = bid % 62;
    const int t   = threadIdx.x;
    const int c   = t & 127;
    const int rh  = t >> 7;

    const float* P0 = Cpart + (((size_t)(0 + bb) * 62 + mt) << 14);
    const float* P1 = Cpart + (((size_t)(4 + bb) * 62 + mt) << 14);
    const int v1 = (c >> 3) * 16 + (c & 7);
    const int v2 = v1 + 8;
    const float bb1 = b1[c];
    const float bb2 = b2[c];

    float best = -3.4e38f;
    for (int r = rh * 32; r < rh * 32 + 32; ++r) {
        int o = r * 256;
        float c1 = P0[o + v1] + P1[o + v1] + bb1;
        float c2 = P0[o + v2] + P1[o + v2] + bb2;
        float g  = c1 / (1.f + __expf(-c2));
        best = fmaxf(best, g);
    }
    red[t] = best;
    __syncthreads();
    if (t < 128)
        atomicMax(&outu[bb * 128 + c], ordenc(fmaxf(red[t], red[t + 128])));
}

// ---------------------------------------------------------------------------
// Kernel 4: decode order-encoded uints to floats in place.
// ---------------------------------------------------------------------------
__global__ __launch_bounds__(256) void unmap_out(unsigned* __restrict__ outu) {
    int i = blockIdx.x * 256 + threadIdx.x;
    if (i < 512) {
        unsigned u = outu[i];
        outu[i] = (u & 0x80000000u) ? (u ^ 0x80000000u) : ~u;
    }
}

extern "C" void kernel_launch(void* const* d_in, const int* in_sizes, int n_in,
                              void* d_out, int out_size, void* d_ws, size_t ws_size,
                              hipStream_t stream) {
    const float* x  = (const float*)d_in[0];
    const float* w1 = (const float*)d_in[1];
    const float* b1 = (const float*)d_in[2];
    const float* w2 = (const float*)d_in[3];
    const float* b2 = (const float*)d_in[4];

    uint4*    Bpf   = (uint4*)d_ws;                 // 2 MB fragment-major bf16
    float*    Cpart = (float*)((char*)d_ws + (2u << 20));  // 33 MB partial C
    unsigned* outu  = (unsigned*)d_out;

    pack_w<<<dim3(512), dim3(256), 0, stream>>>(w1, w2, Bpf, outu);

    gemm_part<<<dim3(496), dim3(1024), 0, stream>>>(x, (const uint4*)Bpf, Cpart);

    merge_max<<<dim3(248), dim3(256), 0, stream>>>(Cpart, b1, b2, outu);

    unmap_out<<<dim3(2), dim3(256), 0, stream>>>(outu);
}